// Round 23
// baseline (107.593 us; speedup 1.0000x reference)
//
#include <hip/hip_runtime.h>
#include <math.h>

#define D_MODEL 32
#define S_LEN   2048
#define B_SZ    8
#define NTOK    (B_SZ * S_LEN)
#define LN_EPS  1e-5f
#define LOG2E   1.44269504088896340736f
#define QK_SCALE 0.35355339059327373f   /* 1/sqrt(8) */
#define PROJ_BLKS (NTOK / 8)            /* 2048 blocks per projection matrix */

typedef __attribute__((ext_vector_type(8)))  short    short8b;
typedef __attribute__((ext_vector_type(4)))  short    short4b;
typedef __attribute__((ext_vector_type(4)))  unsigned uint4v;
typedef __attribute__((ext_vector_type(16))) float    f32x16;

__device__ __forceinline__ unsigned short f2bf(float f) {   // RNE f32->bf16
    unsigned u = __builtin_bit_cast(unsigned, f);
    unsigned r = (u + 0x7FFFu + ((u >> 16) & 1u)) >> 16;
    return (unsigned short)r;
}
__device__ __forceinline__ float bf2f(unsigned short h) {
    return __builtin_bit_cast(float, (unsigned)h << 16);
}
__device__ __forceinline__ unsigned cvtpk_bf16(float lo, float hi) {
    unsigned r;
    asm("v_cvt_pk_bf16_f32 %0, %1, %2" : "=v"(r) : "v"(lo), "v"(hi));
    return r;
}

// Chunk-major layouts (shorts):
//  QHC/QLC: (((b*64 + qt)*4 + h)*32 + q)*8 + d          (1 MB each)
//  KC:      ((((b*64 + ch)*4 + h)*2 + half)*32 + k)*8+d (2 MB, hi|lo halves)
//  VC:      (((b*64 + ch)*4 + h)*8 + dv)*32 + k         (1 MB)

// ---------------------------------------------------------------------------
// Prep: projection only (verbatim R22).
__global__ __launch_bounds__(256) void prep_kernel(
    const float* __restrict__ xQ, const float* __restrict__ xK,
    const float* __restrict__ xV,
    const float* __restrict__ WQ, const float* __restrict__ bQ,
    const float* __restrict__ WK, const float* __restrict__ bK,
    const float* __restrict__ WV, const float* __restrict__ bV,
    unsigned short* __restrict__ QHC, unsigned short* __restrict__ QLC,
    unsigned short* __restrict__ KC,  unsigned short* __restrict__ VC)
{
    int bid = blockIdx.x;
    int t   = threadIdx.x;

    int which = bid / PROJ_BLKS;
    int xb    = bid - which * PROJ_BLKS;
    const float* x; const float* W; const float* bias; float scale;
    if (which == 0)      { x = xQ; W = WQ; bias = bQ; scale = QK_SCALE * LOG2E; }
    else if (which == 1) { x = xK; W = WK; bias = bK; scale = 1.0f; }
    else                 { x = xV; W = WV; bias = bV; scale = 1.0f; }

    __shared__ float xs[8][32];
    __shared__ float Ws[32][32];
    long base = (long)xb * 256;    // 8 rows x 32 cols
    xs[t >> 5][t & 31] = x[base + t];
#pragma unroll
    for (int i = 0; i < 4; ++i) {
        int f = i * 256 + t;
        Ws[f >> 5][f & 31] = W[f];
    }
    __syncthreads();
    int r = t >> 5, j = t & 31;
    float acc = bias[j];
#pragma unroll
    for (int i = 0; i < 32; ++i) acc = fmaf(xs[r][i], Ws[i][j], acc);
    acc *= scale;

    long tok = (long)xb * 8 + r;
    long b   = tok >> 11;
    long ti  = tok & (S_LEN - 1);
    int  ch  = (int)(ti >> 5), kq = (int)(ti & 31);
    int  h   = j >> 3, d = j & 7;

    if (which == 0) {
        size_t qi = ((((size_t)b * 64 + ch) * 4 + h) * 32 + kq) * 8 + d;
        unsigned short hv = f2bf(acc);
        QHC[qi] = hv;
        QLC[qi] = f2bf(acc - bf2f(hv));
    } else if (which == 1) {
        size_t ki = (((((size_t)b * 64 + ch) * 4 + h) * 2 + 0) * 32 + kq) * 8 + d;
        unsigned short hv = f2bf(acc);
        KC[ki]       = hv;                       // half 0 (hi)
        KC[ki + 256] = f2bf(acc - bf2f(hv));     // half 1 (lo)
    } else {
        size_t vi = (((size_t)b * 64 + ch) * 4 + h) * 256 + (size_t)d * 32 + kq;
        VC[vi] = f2bf(acc);
    }
}

// ---------------------------------------------------------------------------
// FULLY-FUSED attention with ASYNC-SPLIT in-loop mask pack (T14):
//   per group g: issue g+1's raw loads -> registers; compute group g;
//   ballot+commit g+1 to LDS; barrier.
// Block = 512 threads = 8 waves = {2 segments x 4 heads} of one (b, 32q-tile).
// Arithmetic per output verbatim R22.
__global__ __launch_bounds__(512, 4) void attn_fused_kernel(
    const unsigned short* __restrict__ QHC, const unsigned short* __restrict__ QLC,
    const unsigned short* __restrict__ KC,  const unsigned short* __restrict__ VC,
    const void* __restrict__ mask,
    const float* __restrict__ WO, const float* __restrict__ bO,
    const float* __restrict__ resid,
    float* __restrict__ sa_out, float* __restrict__ out0)
{
    constexpr int SEGLEN = 1024;
    constexpr int NPT    = SEGLEN / 64;     // 16 pairs per segment
    __shared__ unsigned long long mpk[2][2][32][5];  // [buf][seg][row][c(+pad)]
    __shared__ float ctx_lds[2][32][33];    // [seg][tok][col], padded
    __shared__ float l_lds[2][32][4];       // [seg][tok][head]
    __shared__ float sa_lds[32][33];
    __shared__ float Ws[32][32];

    int raw  = blockIdx.x;                  // 512 blocks
    int cid  = (raw & 7) * 64 + (raw >> 3); // XCD-contiguous (batch==XCD)
    int b    = cid >> 6;
    int qt   = cid & 63;
    int tid  = threadIdx.x;
    int w    = tid >> 6;                    // wave 0..7
    int h    = w & 3;
    int seg  = w >> 2;
    int lane = tid & 63;
    int q    = lane & 31;
    int half = lane >> 5;
    int tok0 = qt * 32;
    long tokbase = (long)b * S_LEN + tok0;
    int k0   = seg * SEGLEN;
    int ch0  = k0 >> 5;

    // stage WO (consumed only after the final barrier)
#pragma unroll
    for (int i = 0; i < 2; ++i) {
        int f = i * 512 + tid;
        Ws[f >> 5][f & 31] = WO[f];
    }

    // mask dtype probe (proven ballot pattern)
    int probe = ((const int*)mask)[lane];
    bool is32 = (__ballot((probe & ~0xFF) == 0) == ~0ULL);

    // ---- async-split pack. word (seg,row,c) bit L = raw[seg*1024+g*256+4L+c]
    // wave w handles rows 4w..4w+3; mload[i*2+s2] holds (row 4w+i, seg s2).
    auto pack_issue = [&](int g, int4* dst) {
#pragma unroll
        for (int i = 0; i < 4; ++i) {
            int r = (w << 2) + i;
            if (is32) {
                const int4* rp = (const int4*)((const int*)mask
                                               + (tokbase + r) * (long)S_LEN);
#pragma unroll
                for (int s2 = 0; s2 < 2; ++s2)
                    dst[i * 2 + s2] = rp[s2 * 256 + g * 64 + lane];
            } else {
                const int* rp = (const int*)((const unsigned char*)mask
                                             + (tokbase + r) * (long)S_LEN);
#pragma unroll
                for (int s2 = 0; s2 < 2; ++s2)
                    dst[i * 2 + s2].x = rp[s2 * 256 + g * 64 + lane];
            }
        }
    };
    auto pack_commit = [&](const int4* src, int buf) {
#pragma unroll
        for (int i = 0; i < 4; ++i) {
            int r = (w << 2) + i;
#pragma unroll
            for (int s2 = 0; s2 < 2; ++s2) {
                int4 v = src[i * 2 + s2];
                unsigned long long b0, b1, b2, b3;
                if (is32) {
                    b0 = __ballot(v.x != 0); b1 = __ballot(v.y != 0);
                    b2 = __ballot(v.z != 0); b3 = __ballot(v.w != 0);
                } else {
                    b0 = __ballot((v.x & 0x000000FF) != 0);
                    b1 = __ballot((v.x & 0x0000FF00) != 0);
                    b2 = __ballot((v.x & 0x00FF0000) != 0);
                    b3 = __ballot((v.x & 0xFF000000u) != 0);
                }
                if (lane == 0) {
                    mpk[buf][s2][r][0] = b0; mpk[buf][s2][r][1] = b1;
                    mpk[buf][s2][r][2] = b2; mpk[buf][s2][r][3] = b3;
                }
            }
        }
    };

    f32x16 zero16;
#pragma unroll
    for (int i = 0; i < 16; ++i) zero16[i] = 0.0f;

    short ovv = (q == 8) ? (short)0x3F80 : (short)0;
    short8b ovf;
#pragma unroll
    for (int i = 0; i < 8; ++i) ovf[i] = ovv;

    size_t qoff = ((((size_t)b * 64 + qt) * 4 + h) * 32 + q) * 8;
    short8b qhf = *(const short8b*)(QHC + qoff);
    short8b qlf = *(const short8b*)(QLC + qoff);
    f32x16 cpv = zero16;

    const unsigned short* Kb0 = KC + (((size_t)b * 64) * 4 + h) * 512
                                   + (size_t)half * 256 + (size_t)q * 8;
    const unsigned short* Vb0 = VC + (((size_t)b * 64) * 4 + h) * 256
                                   + (size_t)q * 32 + half * 4;  // valid q<8

    short8b kfA = *(const short8b*)(Kb0 + (size_t)ch0 * 2048);
    short8b kfB = *(const short8b*)(Kb0 + (size_t)(ch0 + 1) * 2048);
    short8b vf1c, vf2c;
    if (q < 8) {
        const unsigned short* vr = Vb0 + (size_t)ch0 * 1024;
        short4b a0 = *(const short4b*)(vr);
        short4b a1 = *(const short4b*)(vr + 8);
        short4b a2 = *(const short4b*)(vr + 16);
        short4b a3 = *(const short4b*)(vr + 24);
        vf1c = __builtin_shufflevector(a0, a1, 0, 1, 2, 3, 4, 5, 6, 7);
        vf2c = __builtin_shufflevector(a2, a3, 0, 1, 2, 3, 4, 5, 6, 7);
    } else { vf1c = ovf; vf2c = ovf; }

    // prologue: pack group 0 synchronously into buffer 0
    {
        int4 m0[8];
        pack_issue(0, m0);
        pack_commit(m0, 0);
    }
    __syncthreads();

#pragma unroll 1
    for (int g = 0; g < 4; ++g) {
        int cur = g & 1;

        // T14 issue phase: fire next group's raw loads into registers
        int4 mload[8];
        if (g + 1 < 4) pack_issue(g + 1, mload);

        unsigned long long mg[4];
        mg[0] = mpk[cur][seg][q][0];
        mg[1] = mpk[cur][seg][q][1];
        mg[2] = mpk[cur][seg][q][2];
        mg[3] = mpk[cur][seg][q][3];

#pragma unroll 1
        for (int p = 0; p < 4; ++p) {
            int pa  = g * 4 + p;
            int chA = ch0 + 2 * pa;
            int chB = chA + 1;

            short8b kfA_n = kfA, kfB_n = kfB;
            if (pa + 1 < NPT) {
                kfA_n = *(const short8b*)(Kb0 + (size_t)(chA + 2) * 2048);
                kfB_n = *(const short8b*)(Kb0 + (size_t)(chB + 2) * 2048);
            }

            unsigned shA = (unsigned)(p * 16 + half);
            unsigned nA[4], nB[4];
#pragma unroll
            for (int c = 0; c < 4; ++c) {
                nA[c] = (unsigned)(mg[c] >> shA);
                nB[c] = (unsigned)(mg[c] >> (shA + 8u));
            }

            __builtin_amdgcn_s_setprio(1);
            f32x16 accA = __builtin_amdgcn_mfma_f32_32x32x16_bf16(kfA, qhf, zero16, 0, 0, 0);
            f32x16 accB = __builtin_amdgcn_mfma_f32_32x32x16_bf16(kfB, qhf, zero16, 0, 0, 0);
            accA = __builtin_amdgcn_mfma_f32_32x32x16_bf16(kfA, qlf, accA, 0, 0, 0);
            accB = __builtin_amdgcn_mfma_f32_32x32x16_bf16(kfB, qlf, accB, 0, 0, 0);
            __builtin_amdgcn_s_setprio(0);

            short8b vf1n, vf2n;
            if (q < 8) {
                const unsigned short* vr = Vb0 + (size_t)chB * 1024;
                short4b a0 = *(const short4b*)(vr);
                short4b a1 = *(const short4b*)(vr + 8);
                short4b a2 = *(const short4b*)(vr + 16);
                short4b a3 = *(const short4b*)(vr + 24);
                vf1n = __builtin_shufflevector(a0, a1, 0, 1, 2, 3, 4, 5, 6, 7);
                vf2n = __builtin_shufflevector(a2, a3, 0, 1, 2, 3, 4, 5, 6, 7);
            } else { vf1n = ovf; vf2n = ovf; }

            {
                unsigned pr[8];
#pragma unroll
                for (int j = 0; j < 8; ++j) {
                    const int c0 = (2 * j) & 3, c1 = (2 * j + 1) & 3;
                    const int s  = 2 * (j >> 1);
                    float p0 = ((nA[c0] >> s) & 1u) ? 0.0f
                             : __builtin_amdgcn_exp2f(accA[2 * j]);
                    float p1 = ((nA[c1] >> s) & 1u) ? 0.0f
                             : __builtin_amdgcn_exp2f(accA[2 * j + 1]);
                    pr[j] = cvtpk_bf16(p0, p1);
                }
                uint4v t1, t2;
                t1.x = pr[0]; t1.y = pr[1]; t1.z = pr[2]; t1.w = pr[3];
                t2.x = pr[4]; t2.y = pr[5]; t2.z = pr[6]; t2.w = pr[7];
                short8b pfa = __builtin_bit_cast(short8b, t1);
                short8b pfb = __builtin_bit_cast(short8b, t2);

                __builtin_amdgcn_s_setprio(1);
                cpv = __builtin_amdgcn_mfma_f32_32x32x16_bf16(vf1c, pfa, cpv, 0, 0, 0);
                cpv = __builtin_amdgcn_mfma_f32_32x32x16_bf16(vf2c, pfb, cpv, 0, 0, 0);
                __builtin_amdgcn_s_setprio(0);
            }

            short8b vf1nn, vf2nn;
            if (pa + 1 < NPT && q < 8) {
                const unsigned short* vr = Vb0 + (size_t)(chA + 2) * 1024;
                short4b a0 = *(const short4b*)(vr);
                short4b a1 = *(const short4b*)(vr + 8);
                short4b a2 = *(const short4b*)(vr + 16);
                short4b a3 = *(const short4b*)(vr + 24);
                vf1nn = __builtin_shufflevector(a0, a1, 0, 1, 2, 3, 4, 5, 6, 7);
                vf2nn = __builtin_shufflevector(a2, a3, 0, 1, 2, 3, 4, 5, 6, 7);
            } else { vf1nn = ovf; vf2nn = ovf; }

            {
                unsigned pr[8];
#pragma unroll
                for (int j = 0; j < 8; ++j) {
                    const int c0 = (2 * j) & 3, c1 = (2 * j + 1) & 3;
                    const int s  = 2 * (j >> 1);
                    float p0 = ((nB[c0] >> s) & 1u) ? 0.0f
                             : __builtin_amdgcn_exp2f(accB[2 * j]);
                    float p1 = ((nB[c1] >> s) & 1u) ? 0.0f
                             : __builtin_amdgcn_exp2f(accB[2 * j + 1]);
                    pr[j] = cvtpk_bf16(p0, p1);
                }
                uint4v t1, t2;
                t1.x = pr[0]; t1.y = pr[1]; t1.z = pr[2]; t1.w = pr[3];
                t2.x = pr[4]; t2.y = pr[5]; t2.z = pr[6]; t2.w = pr[7];
                short8b pfa = __builtin_bit_cast(short8b, t1);
                short8b pfb = __builtin_bit_cast(short8b, t2);

                __builtin_amdgcn_s_setprio(1);
                cpv = __builtin_amdgcn_mfma_f32_32x32x16_bf16(vf1n, pfa, cpv, 0, 0, 0);
                cpv = __builtin_amdgcn_mfma_f32_32x32x16_bf16(vf2n, pfb, cpv, 0, 0, 0);
                __builtin_amdgcn_s_setprio(0);
            }

            kfA = kfA_n;
            kfB = kfB_n;
            vf1c = vf1nn;
            vf2c = vf2nn;
        }

        // T14 commit phase: ballots + LDS stores (loads long since landed)
        if (g + 1 < 4) pack_commit(mload, cur ^ 1);
        __syncthreads();
    }

    // ---- exchange partials through LDS (C_PV: col=q; rows per C/D formula)
    ctx_lds[seg][q][h * 8 + half * 4 + 0] = cpv[0];
    ctx_lds[seg][q][h * 8 + half * 4 + 1] = cpv[1];
    ctx_lds[seg][q][h * 8 + half * 4 + 2] = cpv[2];
    ctx_lds[seg][q][h * 8 + half * 4 + 3] = cpv[3];
    if (half == 0) l_lds[seg][q][h] = cpv[4];
    __syncthreads();

    // ---- combine + sa write (32 tokens x 32 cols; 512 threads, 2 passes)
    int r = (tid >> 5) & 15;
    int j = tid & 31;
#pragma unroll
    for (int pass = 0; pass < 2; ++pass) {
        int tok = pass * 16 + r;
        float L  = l_lds[0][tok][j >> 3] + l_lds[1][tok][j >> 3];
        float cx = ctx_lds[0][tok][j] + ctx_lds[1][tok][j];
        float sa = cx / L;
        sa_lds[tok][j] = sa;
        sa_out[(tokbase + tok) * 32 + j] = sa;
    }
    __syncthreads();

    // ---- O-projection + residual + LayerNorm
#pragma unroll
    for (int pass = 0; pass < 2; ++pass) {
        int tok = pass * 16 + r;
        long grow = (tokbase + tok) * 32;
        float y = bO[j] + resid[grow + j];
#pragma unroll
        for (int i = 0; i < 32; ++i) y = fmaf(sa_lds[tok][i], Ws[i][j], y);

        float sum = y;
#pragma unroll
        for (int o = 16; o >= 1; o >>= 1) sum += __shfl_xor(sum, o, 32);
        float mu = sum * (1.0f / 32.0f);
        float d  = y - mu;
        float sq = d * d;
#pragma unroll
        for (int o = 16; o >= 1; o >>= 1) sq += __shfl_xor(sq, o, 32);
        float var = sq * (1.0f / 32.0f);
        out0[grow + j] = d * rsqrtf(var + LN_EPS);
    }
}

// ---------------------------------------------------------------------------
extern "C" void kernel_launch(void* const* d_in, const int* in_sizes, int n_in,
                              void* d_out, int out_size, void* d_ws, size_t ws_size,
                              hipStream_t stream)
{
    const float* inQ = (const float*)d_in[0];
    const float* inK = (const float*)d_in[1];
    const float* inV = (const float*)d_in[2];
    const void*  mask = d_in[3];
    const float* WQ = (const float*)d_in[4];
    const float* bQ = (const float*)d_in[5];
    const float* WK = (const float*)d_in[6];
    const float* bK = (const float*)d_in[7];
    const float* WV = (const float*)d_in[8];
    const float* bV = (const float*)d_in[9];
    const float* WO = (const float*)d_in[10];
    const float* bO = (const float*)d_in[11];

    float* out0 = (float*)d_out;                    // layernorm output
    float* sa   = (float*)d_out + (long)NTOK * 32;  // self_attn output

    char* ws = (char*)d_ws;
    unsigned short* QHC = (unsigned short*)(ws + 256);
    unsigned short* QLC = QHC + (size_t)NTOK * 32;
    unsigned short* KC  = QLC + (size_t)NTOK * 32;
    unsigned short* VC  = KC  + (size_t)NTOK * 64;

    prep_kernel<<<3 * PROJ_BLKS, 256, 0, stream>>>(
        inQ, inK, inV, WQ, bQ, WK, bK, WV, bV, QHC, QLC, KC, VC);

    attn_fused_kernel<<<B_SZ * 64, 512, 0, stream>>>(
        QHC, QLC, KC, VC, mask, WO, bO, inQ, sa, out0);
}

// Round 24
// 104.397 us; speedup vs baseline: 1.0306x; 1.0306x over previous
//
#include <hip/hip_runtime.h>
#include <math.h>

#define D_MODEL 32
#define S_LEN   2048
#define B_SZ    8
#define NTOK    (B_SZ * S_LEN)
#define LN_EPS  1e-5f
#define LOG2E   1.44269504088896340736f
#define QK_SCALE 0.35355339059327373f   /* 1/sqrt(8) */
#define PROJ_BLKS (NTOK / 8)            /* 2048 blocks per projection matrix */

typedef __attribute__((ext_vector_type(8)))  short    short8b;
typedef __attribute__((ext_vector_type(4)))  short    short4b;
typedef __attribute__((ext_vector_type(4)))  unsigned uint4v;
typedef __attribute__((ext_vector_type(16))) float    f32x16;

__device__ __forceinline__ unsigned short f2bf(float f) {   // RNE f32->bf16
    unsigned u = __builtin_bit_cast(unsigned, f);
    unsigned r = (u + 0x7FFFu + ((u >> 16) & 1u)) >> 16;
    return (unsigned short)r;
}
__device__ __forceinline__ float bf2f(unsigned short h) {
    return __builtin_bit_cast(float, (unsigned)h << 16);
}
__device__ __forceinline__ unsigned cvtpk_bf16(float lo, float hi) {
    unsigned r;
    asm("v_cvt_pk_bf16_f32 %0, %1, %2" : "=v"(r) : "v"(lo), "v"(hi));
    return r;
}

// Chunk-major layouts (shorts):
//  QHC/QLC: (((b*64 + qt)*4 + h)*32 + q)*8 + d          (1 MB each)
//  KC:      ((((b*64 + ch)*4 + h)*2 + half)*32 + k)*8+d (2 MB, hi|lo halves)
//  VC:      (((b*64 + ch)*4 + h)*8 + dv)*32 + k         (1 MB)

// ---------------------------------------------------------------------------
// Prep: projection only (verbatim R22).
__global__ __launch_bounds__(256) void prep_kernel(
    const float* __restrict__ xQ, const float* __restrict__ xK,
    const float* __restrict__ xV,
    const float* __restrict__ WQ, const float* __restrict__ bQ,
    const float* __restrict__ WK, const float* __restrict__ bK,
    const float* __restrict__ WV, const float* __restrict__ bV,
    unsigned short* __restrict__ QHC, unsigned short* __restrict__ QLC,
    unsigned short* __restrict__ KC,  unsigned short* __restrict__ VC)
{
    int bid = blockIdx.x;
    int t   = threadIdx.x;

    int which = bid / PROJ_BLKS;
    int xb    = bid - which * PROJ_BLKS;
    const float* x; const float* W; const float* bias; float scale;
    if (which == 0)      { x = xQ; W = WQ; bias = bQ; scale = QK_SCALE * LOG2E; }
    else if (which == 1) { x = xK; W = WK; bias = bK; scale = 1.0f; }
    else                 { x = xV; W = WV; bias = bV; scale = 1.0f; }

    __shared__ float xs[8][32];
    __shared__ float Ws[32][32];
    long base = (long)xb * 256;    // 8 rows x 32 cols
    xs[t >> 5][t & 31] = x[base + t];
#pragma unroll
    for (int i = 0; i < 4; ++i) {
        int f = i * 256 + t;
        Ws[f >> 5][f & 31] = W[f];
    }
    __syncthreads();
    int r = t >> 5, j = t & 31;
    float acc = bias[j];
#pragma unroll
    for (int i = 0; i < 32; ++i) acc = fmaf(xs[r][i], Ws[i][j], acc);
    acc *= scale;

    long tok = (long)xb * 8 + r;
    long b   = tok >> 11;
    long ti  = tok & (S_LEN - 1);
    int  ch  = (int)(ti >> 5), kq = (int)(ti & 31);
    int  h   = j >> 3, d = j & 7;

    if (which == 0) {
        size_t qi = ((((size_t)b * 64 + ch) * 4 + h) * 32 + kq) * 8 + d;
        unsigned short hv = f2bf(acc);
        QHC[qi] = hv;
        QLC[qi] = f2bf(acc - bf2f(hv));
    } else if (which == 1) {
        size_t ki = (((((size_t)b * 64 + ch) * 4 + h) * 2 + 0) * 32 + kq) * 8 + d;
        unsigned short hv = f2bf(acc);
        KC[ki]       = hv;                       // half 0 (hi)
        KC[ki + 256] = f2bf(acc - bf2f(hv));     // half 1 (lo)
    } else {
        size_t vi = (((size_t)b * 64 + ch) * 4 + h) * 256 + (size_t)d * 32 + kq;
        VC[vi] = f2bf(acc);
    }
}

// ---------------------------------------------------------------------------
// FULLY-FUSED attention, T14 async-split mask pack with NAMED registers
// (no private arrays / pointer interfaces -> no scratch). Per group g:
//   issue g+1's 8 raw loads into named int4 regs; compute pairs 0-1;
//   ballot+commit; compute pairs 2-3; barrier.
// Block = 512 threads = 8 waves = {2 seg x 4 head} of one (b, 32q-tile).
// Arithmetic per output verbatim R22.
__global__ __launch_bounds__(512, 4) void attn_fused_kernel(
    const unsigned short* __restrict__ QHC, const unsigned short* __restrict__ QLC,
    const unsigned short* __restrict__ KC,  const unsigned short* __restrict__ VC,
    const void* __restrict__ mask,
    const float* __restrict__ WO, const float* __restrict__ bO,
    const float* __restrict__ resid,
    float* __restrict__ sa_out, float* __restrict__ out0)
{
    constexpr int SEGLEN = 1024;
    constexpr int NPT    = SEGLEN / 64;     // 16 pairs per segment
    __shared__ unsigned long long mpk[2][2][32][5];  // [buf][seg][row][c(+pad)]
    __shared__ float ctx_lds[2][32][33];    // [seg][tok][col], padded
    __shared__ float l_lds[2][32][4];       // [seg][tok][head]
    __shared__ float sa_lds[32][33];
    __shared__ float Ws[32][32];

    int raw  = blockIdx.x;                  // 512 blocks
    int cid  = (raw & 7) * 64 + (raw >> 3); // XCD-contiguous (batch==XCD)
    int b    = cid >> 6;
    int qt   = cid & 63;
    int tid  = threadIdx.x;
    int w    = tid >> 6;                    // wave 0..7
    int h    = w & 3;
    int seg  = w >> 2;
    int lane = tid & 63;
    int q    = lane & 31;
    int half = lane >> 5;
    int tok0 = qt * 32;
    long tokbase = (long)b * S_LEN + tok0;
    int k0   = seg * SEGLEN;
    int ch0  = k0 >> 5;

    // stage WO (consumed only after the final barrier)
#pragma unroll
    for (int i = 0; i < 2; ++i) {
        int f = i * 512 + tid;
        Ws[f >> 5][f & 31] = WO[f];
    }

    // mask dtype probe (proven ballot pattern)
    int probe = ((const int*)mask)[lane];
    bool is32 = (__ballot((probe & ~0xFF) == 0) == ~0ULL);

    // row pointers for this wave's 4 mask rows (int32 / byte views)
    long rb = tokbase + (w << 2);
    const int4* r32_0 = (const int4*)((const int*)mask + (rb + 0) * (long)S_LEN);
    const int4* r32_1 = (const int4*)((const int*)mask + (rb + 1) * (long)S_LEN);
    const int4* r32_2 = (const int4*)((const int*)mask + (rb + 2) * (long)S_LEN);
    const int4* r32_3 = (const int4*)((const int*)mask + (rb + 3) * (long)S_LEN);
    const int* r8_0 = (const int*)((const unsigned char*)mask + (rb + 0) * (long)S_LEN);
    const int* r8_1 = (const int*)((const unsigned char*)mask + (rb + 1) * (long)S_LEN);
    const int* r8_2 = (const int*)((const unsigned char*)mask + (rb + 2) * (long)S_LEN);
    const int* r8_3 = (const int*)((const unsigned char*)mask + (rb + 3) * (long)S_LEN);

    // named mask-load registers: mR_S = (row 4w+R, seg S)
    int4 m0_0, m0_1, m1_0, m1_1, m2_0, m2_1, m3_0, m3_1;

#define MASK_ISSUE(G)                                                        \
    if (is32) {                                                              \
        m0_0 = r32_0[(G) * 64 + lane]; m0_1 = r32_0[256 + (G) * 64 + lane];  \
        m1_0 = r32_1[(G) * 64 + lane]; m1_1 = r32_1[256 + (G) * 64 + lane];  \
        m2_0 = r32_2[(G) * 64 + lane]; m2_1 = r32_2[256 + (G) * 64 + lane];  \
        m3_0 = r32_3[(G) * 64 + lane]; m3_1 = r32_3[256 + (G) * 64 + lane];  \
    } else {                                                                 \
        m0_0.x = r8_0[(G) * 64 + lane]; m0_1.x = r8_0[256 + (G) * 64 + lane];\
        m1_0.x = r8_1[(G) * 64 + lane]; m1_1.x = r8_1[256 + (G) * 64 + lane];\
        m2_0.x = r8_2[(G) * 64 + lane]; m2_1.x = r8_2[256 + (G) * 64 + lane];\
        m3_0.x = r8_3[(G) * 64 + lane]; m3_1.x = r8_3[256 + (G) * 64 + lane];\
    }

#define CMT1(MV, RI, S2, BUF)                                                \
    {                                                                        \
        unsigned long long c0, c1, c2, c3;                                   \
        if (is32) {                                                          \
            c0 = __ballot((MV).x != 0); c1 = __ballot((MV).y != 0);          \
            c2 = __ballot((MV).z != 0); c3 = __ballot((MV).w != 0);          \
        } else {                                                             \
            c0 = __ballot(((MV).x & 0x000000FF) != 0);                       \
            c1 = __ballot(((MV).x & 0x0000FF00) != 0);                       \
            c2 = __ballot(((MV).x & 0x00FF0000) != 0);                       \
            c3 = __ballot(((MV).x & 0xFF000000u) != 0);                      \
        }                                                                    \
        if (lane == 0) {                                                     \
            mpk[BUF][S2][(w << 2) + (RI)][0] = c0;                           \
            mpk[BUF][S2][(w << 2) + (RI)][1] = c1;                           \
            mpk[BUF][S2][(w << 2) + (RI)][2] = c2;                           \
            mpk[BUF][S2][(w << 2) + (RI)][3] = c3;                           \
        }                                                                    \
    }

#define MASK_COMMIT(BUF)                                                     \
    CMT1(m0_0, 0, 0, BUF) CMT1(m0_1, 0, 1, BUF)                              \
    CMT1(m1_0, 1, 0, BUF) CMT1(m1_1, 1, 1, BUF)                              \
    CMT1(m2_0, 2, 0, BUF) CMT1(m2_1, 2, 1, BUF)                              \
    CMT1(m3_0, 3, 0, BUF) CMT1(m3_1, 3, 1, BUF)

    f32x16 zero16;
#pragma unroll
    for (int i = 0; i < 16; ++i) zero16[i] = 0.0f;

    short ovv = (q == 8) ? (short)0x3F80 : (short)0;
    short8b ovf;
#pragma unroll
    for (int i = 0; i < 8; ++i) ovf[i] = ovv;

    size_t qoff = ((((size_t)b * 64 + qt) * 4 + h) * 32 + q) * 8;
    short8b qhf = *(const short8b*)(QHC + qoff);
    short8b qlf = *(const short8b*)(QLC + qoff);
    f32x16 cpv = zero16;

    const unsigned short* Kb0 = KC + (((size_t)b * 64) * 4 + h) * 512
                                   + (size_t)half * 256 + (size_t)q * 8;
    const unsigned short* Vb0 = VC + (((size_t)b * 64) * 4 + h) * 256
                                   + (size_t)q * 32 + half * 4;  // valid q<8

    short8b kfA = *(const short8b*)(Kb0 + (size_t)ch0 * 2048);
    short8b kfB = *(const short8b*)(Kb0 + (size_t)(ch0 + 1) * 2048);
    short8b vf1c, vf2c;
    if (q < 8) {
        const unsigned short* vr = Vb0 + (size_t)ch0 * 1024;
        short4b a0 = *(const short4b*)(vr);
        short4b a1 = *(const short4b*)(vr + 8);
        short4b a2 = *(const short4b*)(vr + 16);
        short4b a3 = *(const short4b*)(vr + 24);
        vf1c = __builtin_shufflevector(a0, a1, 0, 1, 2, 3, 4, 5, 6, 7);
        vf2c = __builtin_shufflevector(a2, a3, 0, 1, 2, 3, 4, 5, 6, 7);
    } else { vf1c = ovf; vf2c = ovf; }

    // prologue: pack group 0 synchronously into buffer 0
    MASK_ISSUE(0)
    MASK_COMMIT(0)
    __syncthreads();

    // ---- one (group, pair) compute step; PP is a literal 0..3 ------------
#define PAIR_BODY(G, PP)                                                     \
    {                                                                        \
        int pa  = (G) * 4 + (PP);                                            \
        int chA = ch0 + 2 * pa;                                              \
        int chB = chA + 1;                                                   \
        short8b kfA_n = kfA, kfB_n = kfB;                                    \
        if (pa + 1 < NPT) {                                                  \
            kfA_n = *(const short8b*)(Kb0 + (size_t)(chA + 2) * 2048);       \
            kfB_n = *(const short8b*)(Kb0 + (size_t)(chB + 2) * 2048);       \
        }                                                                    \
        unsigned shA = (unsigned)((PP) * 16 + half);                         \
        unsigned nA[4], nB[4];                                               \
        _Pragma("unroll")                                                    \
        for (int c = 0; c < 4; ++c) {                                        \
            nA[c] = (unsigned)(mg[c] >> shA);                                \
            nB[c] = (unsigned)(mg[c] >> (shA + 8u));                         \
        }                                                                    \
        __builtin_amdgcn_s_setprio(1);                                       \
        f32x16 accA = __builtin_amdgcn_mfma_f32_32x32x16_bf16(kfA, qhf, zero16, 0, 0, 0); \
        f32x16 accB = __builtin_amdgcn_mfma_f32_32x32x16_bf16(kfB, qhf, zero16, 0, 0, 0); \
        accA = __builtin_amdgcn_mfma_f32_32x32x16_bf16(kfA, qlf, accA, 0, 0, 0); \
        accB = __builtin_amdgcn_mfma_f32_32x32x16_bf16(kfB, qlf, accB, 0, 0, 0); \
        __builtin_amdgcn_s_setprio(0);                                       \
        short8b vf1n, vf2n;                                                  \
        if (q < 8) {                                                         \
            const unsigned short* vr = Vb0 + (size_t)chB * 1024;             \
            short4b a0 = *(const short4b*)(vr);                              \
            short4b a1 = *(const short4b*)(vr + 8);                          \
            short4b a2 = *(const short4b*)(vr + 16);                         \
            short4b a3 = *(const short4b*)(vr + 24);                         \
            vf1n = __builtin_shufflevector(a0, a1, 0, 1, 2, 3, 4, 5, 6, 7);  \
            vf2n = __builtin_shufflevector(a2, a3, 0, 1, 2, 3, 4, 5, 6, 7);  \
        } else { vf1n = ovf; vf2n = ovf; }                                   \
        {                                                                    \
            unsigned pr[8];                                                  \
            _Pragma("unroll")                                                \
            for (int j2 = 0; j2 < 8; ++j2) {                                 \
                const int c0 = (2 * j2) & 3, c1 = (2 * j2 + 1) & 3;          \
                const int s  = 2 * (j2 >> 1);                                \
                float p0 = ((nA[c0] >> s) & 1u) ? 0.0f                       \
                         : __builtin_amdgcn_exp2f(accA[2 * j2]);             \
                float p1 = ((nA[c1] >> s) & 1u) ? 0.0f                       \
                         : __builtin_amdgcn_exp2f(accA[2 * j2 + 1]);         \
                pr[j2] = cvtpk_bf16(p0, p1);                                 \
            }                                                                \
            uint4v t1, t2;                                                   \
            t1.x = pr[0]; t1.y = pr[1]; t1.z = pr[2]; t1.w = pr[3];          \
            t2.x = pr[4]; t2.y = pr[5]; t2.z = pr[6]; t2.w = pr[7];          \
            short8b pfa = __builtin_bit_cast(short8b, t1);                   \
            short8b pfb = __builtin_bit_cast(short8b, t2);                   \
            __builtin_amdgcn_s_setprio(1);                                   \
            cpv = __builtin_amdgcn_mfma_f32_32x32x16_bf16(vf1c, pfa, cpv, 0, 0, 0); \
            cpv = __builtin_amdgcn_mfma_f32_32x32x16_bf16(vf2c, pfb, cpv, 0, 0, 0); \
            __builtin_amdgcn_s_setprio(0);                                   \
        }                                                                    \
        short8b vf1nn, vf2nn;                                                \
        if (pa + 1 < NPT && q < 8) {                                         \
            const unsigned short* vr = Vb0 + (size_t)(chA + 2) * 1024;       \
            short4b a0 = *(const short4b*)(vr);                              \
            short4b a1 = *(const short4b*)(vr + 8);                          \
            short4b a2 = *(const short4b*)(vr + 16);                         \
            short4b a3 = *(const short4b*)(vr + 24);                         \
            vf1nn = __builtin_shufflevector(a0, a1, 0, 1, 2, 3, 4, 5, 6, 7); \
            vf2nn = __builtin_shufflevector(a2, a3, 0, 1, 2, 3, 4, 5, 6, 7); \
        } else { vf1nn = ovf; vf2nn = ovf; }                                 \
        {                                                                    \
            unsigned pr[8];                                                  \
            _Pragma("unroll")                                                \
            for (int j2 = 0; j2 < 8; ++j2) {                                 \
                const int c0 = (2 * j2) & 3, c1 = (2 * j2 + 1) & 3;          \
                const int s  = 2 * (j2 >> 1);                                \
                float p0 = ((nB[c0] >> s) & 1u) ? 0.0f                       \
                         : __builtin_amdgcn_exp2f(accB[2 * j2]);             \
                float p1 = ((nB[c1] >> s) & 1u) ? 0.0f                       \
                         : __builtin_amdgcn_exp2f(accB[2 * j2 + 1]);         \
                pr[j2] = cvtpk_bf16(p0, p1);                                 \
            }                                                                \
            uint4v t1, t2;                                                   \
            t1.x = pr[0]; t1.y = pr[1]; t1.z = pr[2]; t1.w = pr[3];          \
            t2.x = pr[4]; t2.y = pr[5]; t2.z = pr[6]; t2.w = pr[7];          \
            short8b pfa = __builtin_bit_cast(short8b, t1);                   \
            short8b pfb = __builtin_bit_cast(short8b, t2);                   \
            __builtin_amdgcn_s_setprio(1);                                   \
            cpv = __builtin_amdgcn_mfma_f32_32x32x16_bf16(vf1n, pfa, cpv, 0, 0, 0); \
            cpv = __builtin_amdgcn_mfma_f32_32x32x16_bf16(vf2n, pfb, cpv, 0, 0, 0); \
            __builtin_amdgcn_s_setprio(0);                                   \
        }                                                                    \
        kfA = kfA_n; kfB = kfB_n; vf1c = vf1nn; vf2c = vf2nn;                \
    }

#pragma unroll 1
    for (int g = 0; g < 4; ++g) {
        int cur = g & 1;

        // T14 issue: fire next group's raw loads into NAMED registers
        if (g + 1 < 4) { MASK_ISSUE(g + 1) }

        unsigned long long mg[4];
        mg[0] = mpk[cur][seg][q][0];
        mg[1] = mpk[cur][seg][q][1];
        mg[2] = mpk[cur][seg][q][2];
        mg[3] = mpk[cur][seg][q][3];

        PAIR_BODY(g, 0)
        PAIR_BODY(g, 1)

        // T14 commit: ballots + LDS stores (loads have landed under pairs 0-1)
        if (g + 1 < 4) { MASK_COMMIT(cur ^ 1) }

        PAIR_BODY(g, 2)
        PAIR_BODY(g, 3)

        __syncthreads();
    }
#undef PAIR_BODY
#undef MASK_COMMIT
#undef CMT1
#undef MASK_ISSUE

    // ---- exchange partials through LDS (C_PV: col=q; rows per C/D formula)
    ctx_lds[seg][q][h * 8 + half * 4 + 0] = cpv[0];
    ctx_lds[seg][q][h * 8 + half * 4 + 1] = cpv[1];
    ctx_lds[seg][q][h * 8 + half * 4 + 2] = cpv[2];
    ctx_lds[seg][q][h * 8 + half * 4 + 3] = cpv[3];
    if (half == 0) l_lds[seg][q][h] = cpv[4];
    __syncthreads();

    // ---- combine + sa write (32 tokens x 32 cols; 512 threads, 2 passes)
    int r = (tid >> 5) & 15;
    int j = tid & 31;
#pragma unroll
    for (int pass = 0; pass < 2; ++pass) {
        int tok = pass * 16 + r;
        float L  = l_lds[0][tok][j >> 3] + l_lds[1][tok][j >> 3];
        float cx = ctx_lds[0][tok][j] + ctx_lds[1][tok][j];
        float sa = cx / L;
        sa_lds[tok][j] = sa;
        sa_out[(tokbase + tok) * 32 + j] = sa;
    }
    __syncthreads();

    // ---- O-projection + residual + LayerNorm
#pragma unroll
    for (int pass = 0; pass < 2; ++pass) {
        int tok = pass * 16 + r;
        long grow = (tokbase + tok) * 32;
        float y = bO[j] + resid[grow + j];
#pragma unroll
        for (int i = 0; i < 32; ++i) y = fmaf(sa_lds[tok][i], Ws[i][j], y);

        float sum = y;
#pragma unroll
        for (int o = 16; o >= 1; o >>= 1) sum += __shfl_xor(sum, o, 32);
        float mu = sum * (1.0f / 32.0f);
        float d  = y - mu;
        float sq = d * d;
#pragma unroll
        for (int o = 16; o >= 1; o >>= 1) sq += __shfl_xor(sq, o, 32);
        float var = sq * (1.0f / 32.0f);
        out0[grow + j] = d * rsqrtf(var + LN_EPS);
    }
}

// ---------------------------------------------------------------------------
extern "C" void kernel_launch(void* const* d_in, const int* in_sizes, int n_in,
                              void* d_out, int out_size, void* d_ws, size_t ws_size,
                              hipStream_t stream)
{
    const float* inQ = (const float*)d_in[0];
    const float* inK = (const float*)d_in[1];
    const float* inV = (const float*)d_in[2];
    const void*  mask = d_in[3];
    const float* WQ = (const float*)d_in[4];
    const float* bQ = (const float*)d_in[5];
    const float* WK = (const float*)d_in[6];
    const float* bK = (const float*)d_in[7];
    const float* WV = (const float*)d_in[8];
    const float* bV = (const float*)d_in[9];
    const float* WO = (const float*)d_in[10];
    const float* bO = (const float*)d_in[11];

    float* out0 = (float*)d_out;                    // layernorm output
    float* sa   = (float*)d_out + (long)NTOK * 32;  // self_attn output

    char* ws = (char*)d_ws;
    unsigned short* QHC = (unsigned short*)(ws + 256);
    unsigned short* QLC = QHC + (size_t)NTOK * 32;
    unsigned short* KC  = QLC + (size_t)NTOK * 32;
    unsigned short* VC  = KC  + (size_t)NTOK * 64;

    prep_kernel<<<3 * PROJ_BLKS, 256, 0, stream>>>(
        inQ, inK, inV, WQ, bQ, WK, bK, WV, bV, QHC, QLC, KC, VC);

    attn_fused_kernel<<<B_SZ * 64, 512, 0, stream>>>(
        QHC, QLC, KC, VC, mask, WO, bO, inQ, sa, out0);
}

// Round 25
// 61.403 us; speedup vs baseline: 1.7523x; 1.7002x over previous
//
#include <hip/hip_runtime.h>
#include <math.h>

#define D_MODEL 32
#define S_LEN   2048
#define B_SZ    8
#define NTOK    (B_SZ * S_LEN)
#define LN_EPS  1e-5f
#define LOG2E   1.44269504088896340736f
#define QK_SCALE 0.35355339059327373f   /* 1/sqrt(8) */
#define PROJ_BLKS (NTOK / 8)            /* 2048 blocks per projection matrix */

typedef __attribute__((ext_vector_type(8)))  short    short8b;
typedef __attribute__((ext_vector_type(4)))  short    short4b;
typedef __attribute__((ext_vector_type(4)))  unsigned uint4v;
typedef __attribute__((ext_vector_type(16))) float    f32x16;

__device__ __forceinline__ unsigned short f2bf(float f) {   // RNE f32->bf16
    unsigned u = __builtin_bit_cast(unsigned, f);
    unsigned r = (u + 0x7FFFu + ((u >> 16) & 1u)) >> 16;
    return (unsigned short)r;
}
__device__ __forceinline__ float bf2f(unsigned short h) {
    return __builtin_bit_cast(float, (unsigned)h << 16);
}
__device__ __forceinline__ unsigned cvtpk_bf16(float lo, float hi) {
    unsigned r;
    asm("v_cvt_pk_bf16_f32 %0, %1, %2" : "=v"(r) : "v"(lo), "v"(hi));
    return r;
}

// Chunk-major layouts (shorts):
//  QHC/QLC: (((b*64 + qt)*4 + h)*32 + q)*8 + d          (1 MB each)
//  KC:      ((((b*64 + ch)*4 + h)*2 + half)*32 + k)*8+d (2 MB, hi|lo halves)
//  VC:      (((b*64 + ch)*4 + h)*8 + dv)*32 + k         (1 MB)

// ---------------------------------------------------------------------------
// Prep: projection only (mask handled inside the fused attn kernel).
__global__ __launch_bounds__(256) void prep_kernel(
    const float* __restrict__ xQ, const float* __restrict__ xK,
    const float* __restrict__ xV,
    const float* __restrict__ WQ, const float* __restrict__ bQ,
    const float* __restrict__ WK, const float* __restrict__ bK,
    const float* __restrict__ WV, const float* __restrict__ bV,
    unsigned short* __restrict__ QHC, unsigned short* __restrict__ QLC,
    unsigned short* __restrict__ KC,  unsigned short* __restrict__ VC)
{
    int bid = blockIdx.x;
    int t   = threadIdx.x;

    int which = bid / PROJ_BLKS;
    int xb    = bid - which * PROJ_BLKS;
    const float* x; const float* W; const float* bias; float scale;
    if (which == 0)      { x = xQ; W = WQ; bias = bQ; scale = QK_SCALE * LOG2E; }
    else if (which == 1) { x = xK; W = WK; bias = bK; scale = 1.0f; }
    else                 { x = xV; W = WV; bias = bV; scale = 1.0f; }

    __shared__ float xs[8][32];
    __shared__ float Ws[32][32];
    long base = (long)xb * 256;    // 8 rows x 32 cols
    xs[t >> 5][t & 31] = x[base + t];
#pragma unroll
    for (int i = 0; i < 4; ++i) {
        int f = i * 256 + t;
        Ws[f >> 5][f & 31] = W[f];
    }
    __syncthreads();
    int r = t >> 5, j = t & 31;
    float acc = bias[j];
#pragma unroll
    for (int i = 0; i < 32; ++i) acc = fmaf(xs[r][i], Ws[i][j], acc);
    acc *= scale;

    long tok = (long)xb * 8 + r;
    long b   = tok >> 11;
    long ti  = tok & (S_LEN - 1);
    int  ch  = (int)(ti >> 5), kq = (int)(ti & 31);
    int  h   = j >> 3, d = j & 7;

    if (which == 0) {
        size_t qi = ((((size_t)b * 64 + ch) * 4 + h) * 32 + kq) * 8 + d;
        unsigned short hv = f2bf(acc);
        QHC[qi] = hv;
        QLC[qi] = f2bf(acc - bf2f(hv));
    } else if (which == 1) {
        size_t ki = (((((size_t)b * 64 + ch) * 4 + h) * 2 + 0) * 32 + kq) * 8 + d;
        unsigned short hv = f2bf(acc);
        KC[ki]       = hv;                       // half 0 (hi)
        KC[ki + 256] = f2bf(acc - bf2f(hv));     // half 1 (lo)
    } else {
        size_t vi = (((size_t)b * 64 + ch) * 4 + h) * 256 + (size_t)d * 32 + kq;
        VC[vi] = f2bf(acc);
    }
}

// ---------------------------------------------------------------------------
// FULLY-FUSED: in-loop mask ballot-pack (double-buffered, overlapped with
// compute) + MFMA flash attention + combine + O-projection + LayerNorm.
// Block = 512 threads = 8 waves = {2 segments x 4 heads} of one (b, 32q-tile).
// Per 256-key group step: pack group g+1's raw mask rows (coalesced int4
// loads + ballots, this block's 32 rows only) while computing group g from
// the LDS-packed words; one __syncthreads per step.
__global__ __launch_bounds__(512, 4) void attn_fused_kernel(
    const unsigned short* __restrict__ QHC, const unsigned short* __restrict__ QLC,
    const unsigned short* __restrict__ KC,  const unsigned short* __restrict__ VC,
    const void* __restrict__ mask,
    const float* __restrict__ WO, const float* __restrict__ bO,
    const float* __restrict__ resid,
    float* __restrict__ sa_out, float* __restrict__ out0)
{
    constexpr int SEGLEN = 1024;
    constexpr int NPT    = SEGLEN / 64;     // 16 pairs per segment
    __shared__ unsigned long long mpk[2][2][32][5];  // [buf][seg][row][c(+pad)]
    __shared__ float ctx_lds[2][32][33];    // [seg][tok][col], padded
    __shared__ float l_lds[2][32][4];       // [seg][tok][head]
    __shared__ float sa_lds[32][33];
    __shared__ float Ws[32][32];

    int raw  = blockIdx.x;                  // 512 blocks
    int cid  = (raw & 7) * 64 + (raw >> 3); // XCD-contiguous (batch==XCD)
    int b    = cid >> 6;
    int qt   = cid & 63;
    int tid  = threadIdx.x;
    int w    = tid >> 6;                    // wave 0..7
    int h    = w & 3;
    int seg  = w >> 2;
    int lane = tid & 63;
    int q    = lane & 31;
    int half = lane >> 5;
    int tok0 = qt * 32;
    long tokbase = (long)b * S_LEN + tok0;
    int k0   = seg * SEGLEN;
    int ch0  = k0 >> 5;

    // stage WO (consumed only after the final barrier)
#pragma unroll
    for (int i = 0; i < 2; ++i) {
        int f = i * 512 + tid;
        Ws[f >> 5][f & 31] = WO[f];
    }

    // mask dtype probe (proven ballot pattern)
    int probe = ((const int*)mask)[lane];
    bool is32 = (__ballot((probe & ~0xFF) == 0) == ~0ULL);

    // ---- pack one 256-key group (both segments) for this block's 32 rows.
    // word (seg,row,c) bit L = mask[row][seg*1024 + g*256 + 4L + c]
    // wave w packs rows 4w..4w+3.
    auto pack_group = [&](int g, int buf) {
#pragma unroll
        for (int i = 0; i < 4; ++i) {
            int r = (w << 2) + i;
            if (is32) {
                const int4* rp = (const int4*)((const int*)mask
                                               + (tokbase + r) * (long)S_LEN);
#pragma unroll
                for (int s2 = 0; s2 < 2; ++s2) {
                    int4 v = rp[s2 * 256 + g * 64 + lane];
                    unsigned long long b0 = __ballot(v.x != 0);
                    unsigned long long b1 = __ballot(v.y != 0);
                    unsigned long long b2 = __ballot(v.z != 0);
                    unsigned long long b3 = __ballot(v.w != 0);
                    if (lane == 0) {
                        mpk[buf][s2][r][0] = b0; mpk[buf][s2][r][1] = b1;
                        mpk[buf][s2][r][2] = b2; mpk[buf][s2][r][3] = b3;
                    }
                }
            } else {
                const int* rp = (const int*)((const unsigned char*)mask
                                             + (tokbase + r) * (long)S_LEN);
#pragma unroll
                for (int s2 = 0; s2 < 2; ++s2) {
                    int v = rp[s2 * 256 + g * 64 + lane];
                    unsigned long long b0 = __ballot((v & 0x000000FF) != 0);
                    unsigned long long b1 = __ballot((v & 0x0000FF00) != 0);
                    unsigned long long b2 = __ballot((v & 0x00FF0000) != 0);
                    unsigned long long b3 = __ballot((v & 0xFF000000u) != 0);
                    if (lane == 0) {
                        mpk[buf][s2][r][0] = b0; mpk[buf][s2][r][1] = b1;
                        mpk[buf][s2][r][2] = b2; mpk[buf][s2][r][3] = b3;
                    }
                }
            }
        }
    };

    f32x16 zero16;
#pragma unroll
    for (int i = 0; i < 16; ++i) zero16[i] = 0.0f;

    short ovv = (q == 8) ? (short)0x3F80 : (short)0;
    short8b ovf;
#pragma unroll
    for (int i = 0; i < 8; ++i) ovf[i] = ovv;

    size_t qoff = ((((size_t)b * 64 + qt) * 4 + h) * 32 + q) * 8;
    short8b qhf = *(const short8b*)(QHC + qoff);
    short8b qlf = *(const short8b*)(QLC + qoff);
    f32x16 cpv = zero16;

    const unsigned short* Kb0 = KC + (((size_t)b * 64) * 4 + h) * 512
                                   + (size_t)half * 256 + (size_t)q * 8;
    const unsigned short* Vb0 = VC + (((size_t)b * 64) * 4 + h) * 256
                                   + (size_t)q * 32 + half * 4;  // valid q<8

    short8b kfA = *(const short8b*)(Kb0 + (size_t)ch0 * 2048);
    short8b kfB = *(const short8b*)(Kb0 + (size_t)(ch0 + 1) * 2048);
    short8b vf1c, vf2c;
    if (q < 8) {
        const unsigned short* vr = Vb0 + (size_t)ch0 * 1024;
        short4b a0 = *(const short4b*)(vr);
        short4b a1 = *(const short4b*)(vr + 8);
        short4b a2 = *(const short4b*)(vr + 16);
        short4b a3 = *(const short4b*)(vr + 24);
        vf1c = __builtin_shufflevector(a0, a1, 0, 1, 2, 3, 4, 5, 6, 7);
        vf2c = __builtin_shufflevector(a2, a3, 0, 1, 2, 3, 4, 5, 6, 7);
    } else { vf1c = ovf; vf2c = ovf; }

    // prologue: pack group 0 into buffer 0
    pack_group(0, 0);
    __syncthreads();

#pragma unroll 1
    for (int g = 0; g < 4; ++g) {
        int cur = g & 1;

        // pack next group into the other buffer (overlaps with compute below)
        if (g + 1 < 4) pack_group(g + 1, cur ^ 1);

        unsigned long long mg[4];
        mg[0] = mpk[cur][seg][q][0];
        mg[1] = mpk[cur][seg][q][1];
        mg[2] = mpk[cur][seg][q][2];
        mg[3] = mpk[cur][seg][q][3];

#pragma unroll 1
        for (int p = 0; p < 4; ++p) {
            int pa  = g * 4 + p;
            int chA = ch0 + 2 * pa;
            int chB = chA + 1;

            short8b kfA_n = kfA, kfB_n = kfB;
            if (pa + 1 < NPT) {
                kfA_n = *(const short8b*)(Kb0 + (size_t)(chA + 2) * 2048);
                kfB_n = *(const short8b*)(Kb0 + (size_t)(chB + 2) * 2048);
            }

            unsigned shA = (unsigned)(p * 16 + half);
            unsigned nA[4], nB[4];
#pragma unroll
            for (int c = 0; c < 4; ++c) {
                nA[c] = (unsigned)(mg[c] >> shA);
                nB[c] = (unsigned)(mg[c] >> (shA + 8u));
            }

            __builtin_amdgcn_s_setprio(1);
            f32x16 accA = __builtin_amdgcn_mfma_f32_32x32x16_bf16(kfA, qhf, zero16, 0, 0, 0);
            f32x16 accB = __builtin_amdgcn_mfma_f32_32x32x16_bf16(kfB, qhf, zero16, 0, 0, 0);
            accA = __builtin_amdgcn_mfma_f32_32x32x16_bf16(kfA, qlf, accA, 0, 0, 0);
            accB = __builtin_amdgcn_mfma_f32_32x32x16_bf16(kfB, qlf, accB, 0, 0, 0);
            __builtin_amdgcn_s_setprio(0);

            short8b vf1n, vf2n;
            if (q < 8) {
                const unsigned short* vr = Vb0 + (size_t)chB * 1024;
                short4b a0 = *(const short4b*)(vr);
                short4b a1 = *(const short4b*)(vr + 8);
                short4b a2 = *(const short4b*)(vr + 16);
                short4b a3 = *(const short4b*)(vr + 24);
                vf1n = __builtin_shufflevector(a0, a1, 0, 1, 2, 3, 4, 5, 6, 7);
                vf2n = __builtin_shufflevector(a2, a3, 0, 1, 2, 3, 4, 5, 6, 7);
            } else { vf1n = ovf; vf2n = ovf; }

            {
                unsigned pr[8];
#pragma unroll
                for (int j = 0; j < 8; ++j) {
                    const int c0 = (2 * j) & 3, c1 = (2 * j + 1) & 3;
                    const int s  = 2 * (j >> 1);
                    float p0 = ((nA[c0] >> s) & 1u) ? 0.0f
                             : __builtin_amdgcn_exp2f(accA[2 * j]);
                    float p1 = ((nA[c1] >> s) & 1u) ? 0.0f
                             : __builtin_amdgcn_exp2f(accA[2 * j + 1]);
                    pr[j] = cvtpk_bf16(p0, p1);
                }
                uint4v t1, t2;
                t1.x = pr[0]; t1.y = pr[1]; t1.z = pr[2]; t1.w = pr[3];
                t2.x = pr[4]; t2.y = pr[5]; t2.z = pr[6]; t2.w = pr[7];
                short8b pfa = __builtin_bit_cast(short8b, t1);
                short8b pfb = __builtin_bit_cast(short8b, t2);

                __builtin_amdgcn_s_setprio(1);
                cpv = __builtin_amdgcn_mfma_f32_32x32x16_bf16(vf1c, pfa, cpv, 0, 0, 0);
                cpv = __builtin_amdgcn_mfma_f32_32x32x16_bf16(vf2c, pfb, cpv, 0, 0, 0);
                __builtin_amdgcn_s_setprio(0);
            }

            short8b vf1nn, vf2nn;
            if (pa + 1 < NPT && q < 8) {
                const unsigned short* vr = Vb0 + (size_t)(chA + 2) * 1024;
                short4b a0 = *(const short4b*)(vr);
                short4b a1 = *(const short4b*)(vr + 8);
                short4b a2 = *(const short4b*)(vr + 16);
                short4b a3 = *(const short4b*)(vr + 24);
                vf1nn = __builtin_shufflevector(a0, a1, 0, 1, 2, 3, 4, 5, 6, 7);
                vf2nn = __builtin_shufflevector(a2, a3, 0, 1, 2, 3, 4, 5, 6, 7);
            } else { vf1nn = ovf; vf2nn = ovf; }

            {
                unsigned pr[8];
#pragma unroll
                for (int j = 0; j < 8; ++j) {
                    const int c0 = (2 * j) & 3, c1 = (2 * j + 1) & 3;
                    const int s  = 2 * (j >> 1);
                    float p0 = ((nB[c0] >> s) & 1u) ? 0.0f
                             : __builtin_amdgcn_exp2f(accB[2 * j]);
                    float p1 = ((nB[c1] >> s) & 1u) ? 0.0f
                             : __builtin_amdgcn_exp2f(accB[2 * j + 1]);
                    pr[j] = cvtpk_bf16(p0, p1);
                }
                uint4v t1, t2;
                t1.x = pr[0]; t1.y = pr[1]; t1.z = pr[2]; t1.w = pr[3];
                t2.x = pr[4]; t2.y = pr[5]; t2.z = pr[6]; t2.w = pr[7];
                short8b pfa = __builtin_bit_cast(short8b, t1);
                short8b pfb = __builtin_bit_cast(short8b, t2);

                __builtin_amdgcn_s_setprio(1);
                cpv = __builtin_amdgcn_mfma_f32_32x32x16_bf16(vf1n, pfa, cpv, 0, 0, 0);
                cpv = __builtin_amdgcn_mfma_f32_32x32x16_bf16(vf2n, pfb, cpv, 0, 0, 0);
                __builtin_amdgcn_s_setprio(0);
            }

            kfA = kfA_n;
            kfB = kfB_n;
            vf1c = vf1nn;
            vf2c = vf2nn;
        }

        __syncthreads();   // next group's pack complete; g's compute reads done
    }

    // ---- exchange partials through LDS (C_PV: col=q; rows per C/D formula)
    ctx_lds[seg][q][h * 8 + half * 4 + 0] = cpv[0];
    ctx_lds[seg][q][h * 8 + half * 4 + 1] = cpv[1];
    ctx_lds[seg][q][h * 8 + half * 4 + 2] = cpv[2];
    ctx_lds[seg][q][h * 8 + half * 4 + 3] = cpv[3];
    if (half == 0) l_lds[seg][q][h] = cpv[4];
    __syncthreads();

    // ---- combine + sa write (32 tokens x 32 cols; 512 threads, 2 passes)
    int r = (tid >> 5) & 15;
    int j = tid & 31;
#pragma unroll
    for (int pass = 0; pass < 2; ++pass) {
        int tok = pass * 16 + r;
        float L  = l_lds[0][tok][j >> 3] + l_lds[1][tok][j >> 3];
        float cx = ctx_lds[0][tok][j] + ctx_lds[1][tok][j];
        float sa = cx / L;
        sa_lds[tok][j] = sa;
        sa_out[(tokbase + tok) * 32 + j] = sa;
    }
    __syncthreads();

    // ---- O-projection + residual + LayerNorm
#pragma unroll
    for (int pass = 0; pass < 2; ++pass) {
        int tok = pass * 16 + r;
        long grow = (tokbase + tok) * 32;
        float y = bO[j] + resid[grow + j];
#pragma unroll
        for (int i = 0; i < 32; ++i) y = fmaf(sa_lds[tok][i], Ws[i][j], y);

        float sum = y;
#pragma unroll
        for (int o = 16; o >= 1; o >>= 1) sum += __shfl_xor(sum, o, 32);
        float mu = sum * (1.0f / 32.0f);
        float d  = y - mu;
        float sq = d * d;
#pragma unroll
        for (int o = 16; o >= 1; o >>= 1) sq += __shfl_xor(sq, o, 32);
        float var = sq * (1.0f / 32.0f);
        out0[grow + j] = d * rsqrtf(var + LN_EPS);
    }
}

// ---------------------------------------------------------------------------
extern "C" void kernel_launch(void* const* d_in, const int* in_sizes, int n_in,
                              void* d_out, int out_size, void* d_ws, size_t ws_size,
                              hipStream_t stream)
{
    const float* inQ = (const float*)d_in[0];
    const float* inK = (const float*)d_in[1];
    const float* inV = (const float*)d_in[2];
    const void*  mask = d_in[3];
    const float* WQ = (const float*)d_in[4];
    const float* bQ = (const float*)d_in[5];
    const float* WK = (const float*)d_in[6];
    const float* bK = (const float*)d_in[7];
    const float* WV = (const float*)d_in[8];
    const float* bV = (const float*)d_in[9];
    const float* WO = (const float*)d_in[10];
    const float* bO = (const float*)d_in[11];

    float* out0 = (float*)d_out;                    // layernorm output
    float* sa   = (float*)d_out + (long)NTOK * 32;  // self_attn output

    char* ws = (char*)d_ws;
    unsigned short* QHC = (unsigned short*)(ws + 256);
    unsigned short* QLC = QHC + (size_t)NTOK * 32;
    unsigned short* KC  = QLC + (size_t)NTOK * 32;
    unsigned short* VC  = KC  + (size_t)NTOK * 64;

    prep_kernel<<<3 * PROJ_BLKS, 256, 0, stream>>>(
        inQ, inK, inV, WQ, bQ, WK, bK, WV, bV, QHC, QLC, KC, VC);

    attn_fused_kernel<<<B_SZ * 64, 512, 0, stream>>>(
        QHC, QLC, KC, VC, mask, WO, bO, inQ, sa, out0);
}